// Round 3
// baseline (198.139 us; speedup 1.0000x reference)
//
#include <hip/hip_runtime.h>
#include <hip/hip_bf16.h>
#include <math.h>

#define N_S 8192
#define N_T 4096
#define DIN 128
#define NF  64

typedef __attribute__((ext_vector_type(8))) short short8;
typedef __attribute__((ext_vector_type(4))) float f32x4;

__device__ __forceinline__ float lrelu(float x){ return fmaxf(x, 0.1f*x); }

// round-to-nearest-even f32 -> bf16 bits
__device__ __forceinline__ unsigned short f2bf(float x){
  unsigned u = __float_as_uint(x);
  unsigned r = (u + 0x7fffu + ((u >> 16) & 1u)) >> 16;
  return (unsigned short)r;
}

// ---------------- K0: compact A (int32 0/1, 134MB) into row-bit and col-bit masks (4MB each)
__global__ __launch_bounds__(256) void compact_kernel(
    const int* __restrict__ A,
    unsigned long long* __restrict__ RB,   // [N_T][N_S/64] bits of row i over j
    unsigned long long* __restrict__ CB)   // [N_S][N_T/64] bits of col j over i
{
  __shared__ unsigned T[64*65];
  int i0 = blockIdx.x * 64;   // over N_T
  int j0 = blockIdx.y * 64;   // over N_S
  int t = threadIdx.x, w = t >> 6, l = t & 63;
  #pragma unroll 4
  for (int it = 0; it < 16; ++it) {
    int r = w*16 + it;
    unsigned m = A[(size_t)(i0 + r)*N_S + j0 + l] > 0 ? 1u : 0u;
    unsigned long long bits = __ballot(m);
    if (l == 0) RB[(size_t)(i0 + r)*(N_S/64) + (j0 >> 6)] = bits;
    T[r*65 + l] = m;
  }
  __syncthreads();
  #pragma unroll 4
  for (int it = 0; it < 16; ++it) {
    int c = w*16 + it;
    unsigned long long bits = __ballot(T[l*65 + c]);
    if (l == 0) CB[(size_t)(j0 + c)*(N_T/64) + (i0 >> 6)] = bits;
  }
}

// ---------------- K1: projections. Writes bf16 TRANSPOSED XT[f][row] for the MFMA B-operand,
// plus f32 attention vectors Whst = Whs@a_s, Whtt = Wht@a_t.
__global__ __launch_bounds__(256) void proj_kernel(
    const float* __restrict__ hs, const float* __restrict__ ht,
    const float* __restrict__ Ws, const float* __restrict__ Wt,
    const float* __restrict__ a1,
    unsigned short* __restrict__ XsT, unsigned short* __restrict__ XtT,
    float* __restrict__ Whst, float* __restrict__ Whtt)
{
  __shared__ float Wl[DIN*NF];
  __shared__ float hrow[4*DIN];
  int b = blockIdx.x;
  bool is_s = b < (N_S/4);
  const float* h; const float* W; const float* av;
  unsigned short* XT; float* dout; int r0, NR;
  if (is_s) { r0 = b*4;           h = hs; W = Ws; av = a1 + 64; XT = XsT; dout = Whst; NR = N_S; }
  else      { r0 = (b - N_S/4)*4; h = ht; W = Wt; av = a1;      XT = XtT; dout = Whtt; NR = N_T; }
  int t = threadIdx.x;
  for (int i = t; i < DIN*NF; i += 256) Wl[i] = W[i];
  for (int i = t; i < 4*DIN;  i += 256) hrow[i] = h[(size_t)r0*DIN + i];
  __syncthreads();
  int f = t & 63, sr = t >> 6;
  float acc = 0.f;
  #pragma unroll 8
  for (int k = 0; k < DIN; ++k) acc += hrow[sr*DIN + k] * Wl[k*NF + f];
  int r = r0 + sr;
  XT[(size_t)f*NR + r] = f2bf(acc);
  float p = acc * av[f];
  #pragma unroll
  for (int o = 32; o > 0; o >>= 1) p += __shfl_xor(p, o, 64);
  if (f == 0) dout[r] = p;
}

// ---------------- K1b: global maxes of Whst (->mx[0]) and Whtt (->mx[1])
__global__ __launch_bounds__(256) void max_kernel(
    const float* __restrict__ Whst, const float* __restrict__ Whtt, float* __restrict__ mx)
{
  const float* src = blockIdx.x == 0 ? Whst : Whtt;
  int n = blockIdx.x == 0 ? N_S : N_T;
  int t = threadIdx.x;
  float m = -1e30f;
  for (int i = t; i < n; i += 256) m = fmaxf(m, src[i]);
  __shared__ float red[4];
  #pragma unroll
  for (int o = 32; o > 0; o >>= 1) m = fmaxf(m, __shfl_xor(m, o, 64));
  if ((t & 63) == 0) red[t >> 6] = m;
  __syncthreads();
  if (t == 0) mx[blockIdx.x] = fmaxf(fmaxf(red[0], red[1]), fmaxf(red[2], red[3]));
}

// ---------------- K2/K3: masked-softmax weighted aggregation via MFMA bf16, bitmask-driven.
// DIR=0 (st): rows u = i in [0,4096), k = j in [0,8192); bits MB=RB; X = Whs^T (XsT)
// DIR=1 (ts): rows u = j in [0,8192), k = i in [0,4096); bits MB=CB; X = Wht^T (XtT)
// w = bit * exp(lrelu(baseU[u]+valK[k]) - lrelu(baseU[u]+mother))   (arg <= 0 always)
// Per wave: 16 output rows x 64 features. One u64 bit-load per lane per 64-k tile.
// Row sums (softmax denominators) via an extra MFMA with an all-ones B operand.
template<int DIR>
__global__ __launch_bounds__(256, 8) void agg_mfma(
    const unsigned long long* __restrict__ MB,
    const float* __restrict__ baseU,
    const float* __restrict__ valK,
    const unsigned short* __restrict__ XT,
    const float* __restrict__ mx,
    float* __restrict__ accG,
    float* __restrict__ sumG,
    int kchunk)
{
  constexpr int NK = (DIR == 0) ? N_S : N_T;   // contraction length / XT row stride
  constexpr int MS = NK / 64;                  // bitmask row stride (u64s)
  int t = threadIdx.x;
  int wave = t >> 6, l = t & 63;
  int row16 = l & 15, grp = l >> 4;            // frag k-offset = grp*8
  int u = blockIdx.x*64 + wave*16 + row16;
  float mother = mx[DIR];
  float bu = baseU[u];
  float Mu = lrelu(bu + mother);
  f32x4 acc[4];
  #pragma unroll
  for (int q = 0; q < 4; ++q) { acc[q][0]=0.f; acc[q][1]=0.f; acc[q][2]=0.f; acc[q][3]=0.f; }
  f32x4 accs; accs[0]=0.f; accs[1]=0.f; accs[2]=0.f; accs[3]=0.f;
  short8 bones;
  #pragma unroll
  for (int j = 0; j < 8; ++j) bones[j] = (short)0x3F80;   // bf16(1.0)
  int kc0 = blockIdx.y * kchunk;

  for (int k0 = kc0; k0 < kc0 + kchunk; k0 += 64) {
    unsigned long long mb = MB[(size_t)u*MS + (k0 >> 6)];
    short8 af0, af1;
    #pragma unroll
    for (int h = 0; h < 2; ++h) {
      int kb = k0 + 32*h + grp*8;
      float4 v0 = *(const float4*)&valK[kb];
      float4 v1 = *(const float4*)&valK[kb + 4];
      float vv[8] = {v0.x, v0.y, v0.z, v0.w, v1.x, v1.y, v1.z, v1.w};
      unsigned bbits = (unsigned)(mb >> (grp*8 + 32*h)) & 0xffu;
      short8 af;
      #pragma unroll
      for (int j = 0; j < 8; ++j) {
        float x = bu + vv[j];
        float e = __expf(lrelu(x) - Mu);
        float wv = ((bbits >> j) & 1u) ? e : 0.f;
        af[j] = (short)f2bf(wv);
      }
      if (h == 0) af0 = af; else af1 = af;
    }
    #pragma unroll
    for (int q = 0; q < 4; ++q) {
      const size_t xb = (size_t)(q*16 + row16) * NK;
      short8 b0 = *(const short8*)&XT[xb + k0 + grp*8];
      short8 b1 = *(const short8*)&XT[xb + k0 + 32 + grp*8];
      acc[q] = __builtin_amdgcn_mfma_f32_16x16x32_bf16(af0, b0, acc[q], 0, 0, 0);
      acc[q] = __builtin_amdgcn_mfma_f32_16x16x32_bf16(af1, b1, acc[q], 0, 0, 0);
    }
    accs = __builtin_amdgcn_mfma_f32_16x16x32_bf16(af0, bones, accs, 0, 0, 0);
    accs = __builtin_amdgcn_mfma_f32_16x16x32_bf16(af1, bones, accs, 0, 0, 0);
  }

  // denominators: D layout col=row16, row=grp*4+r; col 0 lanes hold the sums
  if (row16 == 0) {
    #pragma unroll
    for (int r = 0; r < 4; ++r)
      atomicAdd(&sumG[blockIdx.x*64 + wave*16 + grp*4 + r], accs[r]);
  }

  // C/D layout: col = l&15, row = grp*4 + reg
  #pragma unroll
  for (int q = 0; q < 4; ++q) {
    #pragma unroll
    for (int r = 0; r < 4; ++r) {
      int uo = blockIdx.x*64 + wave*16 + grp*4 + r;
      atomicAdd(&accG[(size_t)uo*NF + q*16 + row16], acc[q][r]);
    }
  }
}

// ---------------- K4: normalize + bias + elu, write both outputs
__global__ __launch_bounds__(256) void finalize_kernel(
    const float* __restrict__ accST, const float* __restrict__ sumST,
    const float* __restrict__ accTS, const float* __restrict__ sumTS,
    const float* __restrict__ bias_s, const float* __restrict__ bias_t,
    float* __restrict__ out)
{
  int idx = blockIdx.x*256 + threadIdx.x;
  const int n0 = N_T*NF;
  float v;
  if (idx < n0) {
    int u = idx >> 6, f = idx & 63;
    float s = sumST[u];
    float r = s > 0.f ? accST[idx]/s : 0.f;
    v = r + bias_s[f];
  } else {
    int i2 = idx - n0;
    int u = i2 >> 6, f = i2 & 63;
    float s = sumTS[u];
    float r = s > 0.f ? accTS[i2]/s : 0.f;
    v = r + bias_t[f];
  }
  out[idx] = v > 0.f ? v : expm1f(v);
}

extern "C" void kernel_launch(void* const* d_in, const int* in_sizes, int n_in,
                              void* d_out, int out_size, void* d_ws, size_t ws_size,
                              hipStream_t stream)
{
  const float* hs     = (const float*)d_in[0];
  const float* ht     = (const float*)d_in[1];
  const int*   A      = (const int*)  d_in[2];
  const float* Ws     = (const float*)d_in[3];
  const float* Wt     = (const float*)d_in[4];
  const float* a1     = (const float*)d_in[5];
  const float* bias_s = (const float*)d_in[6];
  const float* bias_t = (const float*)d_in[7];
  float* out = (float*)d_out;

  unsigned long long* RB = (unsigned long long*)d_ws;        // 4096*128 u64 = 4MB
  unsigned long long* CB = RB + (size_t)N_T*(N_S/64);        // 8192*64  u64 = 4MB
  unsigned short* XsT = (unsigned short*)(CB + (size_t)N_S*(N_T/64)); // 64*8192 bf16
  unsigned short* XtT = XsT + (size_t)NF*N_S;                // 64*4096 bf16
  float* Whst  = (float*)(XtT + (size_t)NF*N_T);             // 8192
  float* Whtt  = Whst + N_S;                                 // 4096
  float* mx    = Whtt + N_T;                                 // 16 (padded)
  float* accST = mx + 16;                                    // 4096*64
  float* sumST = accST + (size_t)N_T*NF;                     // 4096
  float* accTS = sumST + N_T;                                // 8192*64
  float* sumTS = accTS + (size_t)N_S*NF;                     // 8192

  hipMemsetAsync(accST, 0,
                 ((size_t)N_T*NF + N_T + (size_t)N_S*NF + N_S) * sizeof(float), stream);

  compact_kernel<<<dim3(N_T/64, N_S/64), 256, 0, stream>>>(A, RB, CB);
  proj_kernel<<<(N_S + N_T)/4, 256, 0, stream>>>(hs, ht, Ws, Wt, a1, XsT, XtT, Whst, Whtt);
  max_kernel<<<2, 256, 0, stream>>>(Whst, Whtt, mx);
  agg_mfma<0><<<dim3(N_T/64, 32), 256, 0, stream>>>(RB, Whtt, Whst, XsT, mx, accST, sumST, N_S/32);
  agg_mfma<1><<<dim3(N_S/64, 16), 256, 0, stream>>>(CB, Whst, Whtt, XtT, mx, accTS, sumTS, N_T/16);
  finalize_kernel<<<(N_T*NF + N_S*NF)/256, 256, 0, stream>>>(accST, sumST, accTS, sumTS,
                                                             bias_s, bias_t, out);
}

// Round 4
// 150.129 us; speedup vs baseline: 1.3198x; 1.3198x over previous
//
#include <hip/hip_runtime.h>
#include <math.h>

#define N_S 8192
#define N_T 4096
#define DIN 128
#define NF  64
#define SPL0 32
#define SPL1 16

typedef __attribute__((ext_vector_type(8))) short short8;
typedef __attribute__((ext_vector_type(4))) float f32x4;

__device__ __forceinline__ float lrelu(float x){ return fmaxf(x, 0.1f*x); }

// round-to-nearest-even f32 -> bf16 bits
__device__ __forceinline__ unsigned short f2bf(float x){
  unsigned u = __float_as_uint(x);
  unsigned r = (u + 0x7fffu + ((u >> 16) & 1u)) >> 16;
  return (unsigned short)r;
}

// ---------------- K0: compact A (int32 0/1, 134MB) into row-bit and col-bit masks (4MB each)
// Tile 64 rows x 256 cols per block. int4 loads (16 independent per lane), nibble-packed
// LDS tile (stride 65 words, conflict-free), per-thread u64 assembly for RB and CB.
__global__ __launch_bounds__(256) void compact_kernel(
    const int* __restrict__ A,
    unsigned long long* __restrict__ RB,   // [N_T][N_S/64] bits of row i over j
    unsigned long long* __restrict__ CB)   // [N_S][N_T/64] bits of col j over i
{
  __shared__ unsigned T4[16*65];  // [rgrp][word l]: byte rr = nibble(cols 4l..4l+3, row 4*rgrp+rr)
  int i0 = blockIdx.x * 64;
  int j0 = blockIdx.y * 256;
  int t = threadIdx.x, w = t >> 6, l = t & 63;
  int4 v[16];
  #pragma unroll
  for (int it = 0; it < 16; ++it)
    v[it] = *(const int4*)&A[(size_t)(i0 + w*16 + it)*N_S + j0 + 4*l];
  #pragma unroll
  for (int rg = 0; rg < 4; ++rg) {
    unsigned p = 0;
    #pragma unroll
    for (int rr = 0; rr < 4; ++rr) {
      int4 m = v[rg*4 + rr];
      unsigned nib = (m.x > 0 ? 1u : 0u) | (m.y > 0 ? 2u : 0u)
                   | (m.z > 0 ? 4u : 0u) | (m.w > 0 ? 8u : 0u);
      p |= nib << (8*rr);
    }
    T4[(w*4 + rg)*65 + l] = p;
  }
  __syncthreads();
  // RB: thread t -> row r = t&63, colgroup g = t>>6 (64 cols each)
  {
    int r = t & 63, g = t >> 6;
    unsigned long long bits = 0;
    #pragma unroll
    for (int i = 0; i < 16; ++i) {
      unsigned word = T4[(r >> 2)*65 + g*16 + i];
      unsigned nib = (word >> (8*(r & 3))) & 0xFu;
      bits |= (unsigned long long)nib << (4*i);
    }
    RB[(size_t)(i0 + r)*(N_S/64) + (j0 >> 6) + g] = bits;
  }
  // CB: thread t -> col c = t (256 cols), bits over the 64 rows
  {
    int c = t;
    unsigned long long bits = 0;
    #pragma unroll
    for (int rg = 0; rg < 16; ++rg) {
      unsigned word = T4[rg*65 + (c >> 2)];
      unsigned x = (word >> (c & 3)) & 0x01010101u;
      unsigned nib = (x * 0x01020408u) >> 24;   // b0|b1<<1|b2<<2|b3<<3
      bits |= (unsigned long long)(nib & 0xFu) << (4*rg);
    }
    CB[(size_t)(j0 + c)*(N_T/64) + (i0 >> 6)] = bits;
  }
}

// ---------------- K1: projections. Writes bf16 TRANSPOSED XT[f][row] for the MFMA B-operand,
// plus f32 attention vectors Whst = Whs@a_s, Whtt = Wht@a_t.
__global__ __launch_bounds__(256) void proj_kernel(
    const float* __restrict__ hs, const float* __restrict__ ht,
    const float* __restrict__ Ws, const float* __restrict__ Wt,
    const float* __restrict__ a1,
    unsigned short* __restrict__ XsT, unsigned short* __restrict__ XtT,
    float* __restrict__ Whst, float* __restrict__ Whtt)
{
  __shared__ float Wl[DIN*NF];
  __shared__ float hrow[4*DIN];
  int b = blockIdx.x;
  bool is_s = b < (N_S/4);
  const float* h; const float* W; const float* av;
  unsigned short* XT; float* dout; int r0, NR;
  if (is_s) { r0 = b*4;           h = hs; W = Ws; av = a1 + 64; XT = XsT; dout = Whst; NR = N_S; }
  else      { r0 = (b - N_S/4)*4; h = ht; W = Wt; av = a1;      XT = XtT; dout = Whtt; NR = N_T; }
  int t = threadIdx.x;
  for (int i = t; i < DIN*NF; i += 256) Wl[i] = W[i];
  for (int i = t; i < 4*DIN;  i += 256) hrow[i] = h[(size_t)r0*DIN + i];
  __syncthreads();
  int f = t & 63, sr = t >> 6;
  float acc = 0.f;
  #pragma unroll 8
  for (int k = 0; k < DIN; ++k) acc += hrow[sr*DIN + k] * Wl[k*NF + f];
  int r = r0 + sr;
  XT[(size_t)f*NR + r] = f2bf(acc);
  float p = acc * av[f];
  #pragma unroll
  for (int o = 32; o > 0; o >>= 1) p += __shfl_xor(p, o, 64);
  if (f == 0) dout[r] = p;
}

// ---------------- K1b: global maxes of Whst (->mx[0]) and Whtt (->mx[1])
__global__ __launch_bounds__(256) void max_kernel(
    const float* __restrict__ Whst, const float* __restrict__ Whtt, float* __restrict__ mx)
{
  const float* src = blockIdx.x == 0 ? Whst : Whtt;
  int n = blockIdx.x == 0 ? N_S : N_T;
  int t = threadIdx.x;
  float m = -1e30f;
  for (int i = t; i < n; i += 256) m = fmaxf(m, src[i]);
  __shared__ float red[4];
  #pragma unroll
  for (int o = 32; o > 0; o >>= 1) m = fmaxf(m, __shfl_xor(m, o, 64));
  if ((t & 63) == 0) red[t >> 6] = m;
  __syncthreads();
  if (t == 0) mx[blockIdx.x] = fmaxf(fmaxf(red[0], red[1]), fmaxf(red[2], red[3]));
}

// ---------------- K2/K3: masked-softmax weighted aggregation via MFMA bf16, bitmask-driven.
// DIR=0 (st): rows u = i in [0,4096), k = j in [0,8192); bits MB=RB; X = Whs^T (XsT)
// DIR=1 (ts): rows u = j in [0,8192), k = i in [0,4096); bits MB=CB; X = Wht^T (XtT)
// w = bit * exp(lrelu(baseU[u]+valK[k]) - lrelu(baseU[u]+mother))   (arg <= 0 always)
// Row sums (denominators) via an extra MFMA with an all-ones B operand.
// NO atomics: each k-split block stores its partial tile to accP[split] / sumP[split].
template<int DIR>
__global__ __launch_bounds__(256, 8) void agg_mfma(
    const unsigned long long* __restrict__ MB,
    const float* __restrict__ baseU,
    const float* __restrict__ valK,
    const unsigned short* __restrict__ XT,
    const float* __restrict__ mx,
    float* __restrict__ accP,   // [splits][NU][NF]
    float* __restrict__ sumP,   // [splits][NU]
    int kchunk)
{
  constexpr int NK = (DIR == 0) ? N_S : N_T;   // contraction length / XT row stride
  constexpr int NU = (DIR == 0) ? N_T : N_S;   // output rows
  constexpr int MS = NK / 64;                  // bitmask row stride (u64s)
  int t = threadIdx.x;
  int wave = t >> 6, l = t & 63;
  int row16 = l & 15, grp = l >> 4;            // frag k-offset = grp*8
  int u = blockIdx.x*64 + wave*16 + row16;
  float mother = mx[DIR];
  float bu = baseU[u];
  float Mu = lrelu(bu + mother);
  f32x4 acc[4];
  #pragma unroll
  for (int q = 0; q < 4; ++q) { acc[q][0]=0.f; acc[q][1]=0.f; acc[q][2]=0.f; acc[q][3]=0.f; }
  f32x4 accs; accs[0]=0.f; accs[1]=0.f; accs[2]=0.f; accs[3]=0.f;
  short8 bones;
  #pragma unroll
  for (int j = 0; j < 8; ++j) bones[j] = (short)0x3F80;   // bf16(1.0)
  int kc0 = blockIdx.y * kchunk;

  #pragma unroll 2
  for (int k0 = kc0; k0 < kc0 + kchunk; k0 += 64) {
    unsigned long long mb = MB[(size_t)u*MS + (k0 >> 6)];
    short8 af0, af1;
    #pragma unroll
    for (int h = 0; h < 2; ++h) {
      int kb = k0 + 32*h + grp*8;
      float4 v0 = *(const float4*)&valK[kb];
      float4 v1 = *(const float4*)&valK[kb + 4];
      float vv[8] = {v0.x, v0.y, v0.z, v0.w, v1.x, v1.y, v1.z, v1.w};
      unsigned bbits = (unsigned)(mb >> (grp*8 + 32*h)) & 0xffu;
      short8 af;
      #pragma unroll
      for (int j = 0; j < 8; ++j) {
        float x = bu + vv[j];
        float e = __expf(lrelu(x) - Mu);
        float wv = ((bbits >> j) & 1u) ? e : 0.f;
        af[j] = (short)f2bf(wv);
      }
      if (h == 0) af0 = af; else af1 = af;
    }
    #pragma unroll
    for (int q = 0; q < 4; ++q) {
      const size_t xb = (size_t)(q*16 + row16) * NK;
      short8 b0 = *(const short8*)&XT[xb + k0 + grp*8];
      short8 b1 = *(const short8*)&XT[xb + k0 + 32 + grp*8];
      acc[q] = __builtin_amdgcn_mfma_f32_16x16x32_bf16(af0, b0, acc[q], 0, 0, 0);
      acc[q] = __builtin_amdgcn_mfma_f32_16x16x32_bf16(af1, b1, acc[q], 0, 0, 0);
    }
    accs = __builtin_amdgcn_mfma_f32_16x16x32_bf16(af0, bones, accs, 0, 0, 0);
    accs = __builtin_amdgcn_mfma_f32_16x16x32_bf16(af1, bones, accs, 0, 0, 0);
  }

  int split = blockIdx.y;
  // denominators: D layout col=row16, row=grp*4+r; col-0 lanes hold the row sums
  if (row16 == 0) {
    #pragma unroll
    for (int r = 0; r < 4; ++r)
      sumP[(size_t)split*NU + blockIdx.x*64 + wave*16 + grp*4 + r] = accs[r];
  }
  // C/D layout: col = l&15, row = grp*4 + reg
  float* ap = accP + (size_t)split*NU*NF;
  #pragma unroll
  for (int q = 0; q < 4; ++q) {
    #pragma unroll
    for (int r = 0; r < 4; ++r) {
      int uo = blockIdx.x*64 + wave*16 + grp*4 + r;
      ap[(size_t)uo*NF + q*16 + row16] = acc[q][r];
    }
  }
}

// ---------------- K4: reduce partials + normalize + bias + elu, float4-vectorized
__global__ __launch_bounds__(256) void finalize_kernel(
    const float* __restrict__ P0, const float* __restrict__ S0,
    const float* __restrict__ P1, const float* __restrict__ S1,
    const float* __restrict__ bias_s, const float* __restrict__ bias_t,
    float* __restrict__ out)
{
  int tid = blockIdx.x*256 + threadIdx.x;   // one float4 per thread
  const int n0 = N_T*NF/4;
  float4 a = make_float4(0.f, 0.f, 0.f, 0.f);
  float den = 0.f;
  float4 bias;
  if (tid < n0) {
    int u = tid >> 4, fq = (tid & 15)*4;
    #pragma unroll 4
    for (int s = 0; s < SPL0; ++s) {
      float4 p = *(const float4*)&P0[((size_t)s*N_T + u)*NF + fq];
      a.x += p.x; a.y += p.y; a.z += p.z; a.w += p.w;
      den += S0[(size_t)s*N_T + u];
    }
    bias = *(const float4*)&bias_s[fq];
  } else {
    int i2 = tid - n0;
    int u = i2 >> 4, fq = (i2 & 15)*4;
    #pragma unroll 4
    for (int s = 0; s < SPL1; ++s) {
      float4 p = *(const float4*)&P1[((size_t)s*N_S + u)*NF + fq];
      a.x += p.x; a.y += p.y; a.z += p.z; a.w += p.w;
      den += S1[(size_t)s*N_S + u];
    }
    bias = *(const float4*)&bias_t[fq];
  }
  float inv = den > 0.f ? 1.f/den : 0.f;
  float4 v;
  v.x = a.x*inv + bias.x; v.y = a.y*inv + bias.y;
  v.z = a.z*inv + bias.z; v.w = a.w*inv + bias.w;
  v.x = v.x > 0.f ? v.x : expm1f(v.x);
  v.y = v.y > 0.f ? v.y : expm1f(v.y);
  v.z = v.z > 0.f ? v.z : expm1f(v.z);
  v.w = v.w > 0.f ? v.w : expm1f(v.w);
  *(float4*)&out[tid*4] = v;
}

extern "C" void kernel_launch(void* const* d_in, const int* in_sizes, int n_in,
                              void* d_out, int out_size, void* d_ws, size_t ws_size,
                              hipStream_t stream)
{
  const float* hs     = (const float*)d_in[0];
  const float* ht     = (const float*)d_in[1];
  const int*   A      = (const int*)  d_in[2];
  const float* Ws     = (const float*)d_in[3];
  const float* Wt     = (const float*)d_in[4];
  const float* a1     = (const float*)d_in[5];
  const float* bias_s = (const float*)d_in[6];
  const float* bias_t = (const float*)d_in[7];
  float* out = (float*)d_out;

  unsigned long long* RB = (unsigned long long*)d_ws;        // 4096*128 u64 = 4MB
  unsigned long long* CB = RB + (size_t)N_T*(N_S/64);        // 8192*64  u64 = 4MB
  unsigned short* XsT = (unsigned short*)(CB + (size_t)N_S*(N_T/64)); // 1MB
  unsigned short* XtT = XsT + (size_t)NF*N_S;                // 0.5MB
  float* Whst  = (float*)(XtT + (size_t)NF*N_T);             // 8192
  float* Whtt  = Whst + N_S;                                 // 4096
  float* mx    = Whtt + N_T;                                 // 16 (padded)
  float* P0    = mx + 16;                                    // SPL0*4096*64 = 32MB
  float* S0    = P0 + (size_t)SPL0*N_T*NF;                   // SPL0*4096
  float* P1    = S0 + (size_t)SPL0*N_T;                      // SPL1*8192*64 = 32MB
  float* S1    = P1 + (size_t)SPL1*N_S*NF;                   // SPL1*8192

  compact_kernel<<<dim3(N_T/64, N_S/256), 256, 0, stream>>>(A, RB, CB);
  proj_kernel<<<(N_S + N_T)/4, 256, 0, stream>>>(hs, ht, Ws, Wt, a1, XsT, XtT, Whst, Whtt);
  max_kernel<<<2, 256, 0, stream>>>(Whst, Whtt, mx);
  agg_mfma<0><<<dim3(N_T/64, SPL0), 256, 0, stream>>>(RB, Whtt, Whst, XsT, mx, P0, S0, N_S/SPL0);
  agg_mfma<1><<<dim3(N_S/64, SPL1), 256, 0, stream>>>(CB, Whst, Whtt, XtT, mx, P1, S1, N_T/SPL1);
  finalize_kernel<<<(N_T*NF + N_S*NF)/1024, 256, 0, stream>>>(P0, S0, P1, S1,
                                                              bias_s, bias_t, out);
}

// Round 5
// 101.023 us; speedup vs baseline: 1.9613x; 1.4861x over previous
//
#include <hip/hip_runtime.h>
#include <math.h>

#define N_S 8192
#define N_T 4096
#define DIN 128
#define NF  64
#define SPL0 8
#define SPL1 8

typedef __attribute__((ext_vector_type(8))) short short8;
typedef __attribute__((ext_vector_type(4))) float f32x4;
typedef unsigned long long u64;

__device__ __forceinline__ float lrelu(float x){ return fmaxf(x, 0.1f*x); }

// round-to-nearest-even f32 -> bf16 bits
__device__ __forceinline__ unsigned short f2bf(float x){
  unsigned u = __float_as_uint(x);
  unsigned r = (u + 0x7fffu + ((u >> 16) & 1u)) >> 16;
  return (unsigned short)r;
}

// fragment-major bf16 layout: B-frag for MFMA reads 1KB contiguous per wave
// idx(f,k) = (k>>5)*2048 + (f>>4)*512 + ((k>>3)&3)*128 + (f&15)*8 + (k&7)
__device__ __forceinline__ size_t xt2_idx(int f, int k){
  return ((size_t)(k >> 5))*2048 + (size_t)((f >> 4)*512 + ((k >> 3) & 3)*128 + (f & 15)*8 + (k & 7));
}

// ---------------- K1: fused {compact A -> bitmasks} + {projections}
// blocks [0,2048): compact 64x256 tile of A into RBt (k-chunk-major) and CBt
// blocks [2048,5120): proj 4 rows -> XT2 (fragment-major bf16) + Whst/Whtt
__global__ __launch_bounds__(256) void k1_fused(
    const int* __restrict__ A,
    u64* __restrict__ RBt,       // [N_S/64][N_T]  bits of row i over j, chunk-major
    u64* __restrict__ CBt,       // [N_T/64][N_S]  bits of col j over i, chunk-major
    const float* __restrict__ hs, const float* __restrict__ ht,
    const float* __restrict__ Ws, const float* __restrict__ Wt,
    const float* __restrict__ a1,
    unsigned short* __restrict__ XT2s, unsigned short* __restrict__ XT2t,
    float* __restrict__ Whst, float* __restrict__ Whtt)
{
  __shared__ __align__(16) float smem[DIN*NF + 4*DIN];   // 34816 B
  int bx = blockIdx.x;
  int t = threadIdx.x;
  if (bx < 2048) {
    // ---- compact ----
    unsigned* T4 = (unsigned*)smem;      // 16*65 words
    int i0 = (bx & 63) * 64;
    int j0 = (bx >> 6) * 256;
    int w = t >> 6, l = t & 63;
    int4 v[16];
    #pragma unroll
    for (int it = 0; it < 16; ++it)
      v[it] = *(const int4*)&A[(size_t)(i0 + w*16 + it)*N_S + j0 + 4*l];
    #pragma unroll
    for (int rg = 0; rg < 4; ++rg) {
      unsigned p = 0;
      #pragma unroll
      for (int rr = 0; rr < 4; ++rr) {
        int4 m = v[rg*4 + rr];
        unsigned nib = (m.x > 0 ? 1u : 0u) | (m.y > 0 ? 2u : 0u)
                     | (m.z > 0 ? 4u : 0u) | (m.w > 0 ? 8u : 0u);
        p |= nib << (8*rr);
      }
      T4[(w*4 + rg)*65 + l] = p;
    }
    __syncthreads();
    // RB: thread -> row r = t&63, colgroup g = t>>6
    {
      int r = t & 63, g = t >> 6;
      u64 bits = 0;
      #pragma unroll
      for (int i = 0; i < 16; ++i) {
        unsigned word = T4[(r >> 2)*65 + g*16 + i];
        unsigned nib = (word >> (8*(r & 3))) & 0xFu;
        bits |= (u64)nib << (4*i);
      }
      RBt[(size_t)((j0 >> 6) + g)*N_T + i0 + r] = bits;
    }
    // CB: thread -> col c = t
    {
      int c = t;
      u64 bits = 0;
      #pragma unroll
      for (int rg = 0; rg < 16; ++rg) {
        unsigned word = T4[rg*65 + (c >> 2)];
        unsigned x = (word >> (c & 3)) & 0x01010101u;
        unsigned nib = (x * 0x01020408u) >> 24;
        bits |= (u64)(nib & 0xFu) << (4*rg);
      }
      CBt[(size_t)(i0 >> 6)*N_S + j0 + c] = bits;
    }
  } else {
    // ---- proj ----
    int b = bx - 2048;
    float* Wl = smem;
    float* hrow = smem + DIN*NF;
    bool is_s = b < (N_S/4);
    const float* h; const float* W; const float* av;
    unsigned short* XT; float* dout; int r0;
    if (is_s) { r0 = b*4;           h = hs; W = Ws; av = a1 + 64; XT = XT2s; dout = Whst; }
    else      { r0 = (b - N_S/4)*4; h = ht; W = Wt; av = a1;      XT = XT2t; dout = Whtt; }
    for (int i = t; i < DIN*NF; i += 256) Wl[i] = W[i];
    for (int i = t; i < 4*DIN;  i += 256) hrow[i] = h[(size_t)r0*DIN + i];
    __syncthreads();
    int f = t & 63, sr = t >> 6;
    float acc = 0.f;
    #pragma unroll 8
    for (int k = 0; k < DIN; ++k) acc += hrow[sr*DIN + k] * Wl[k*NF + f];
    int r = r0 + sr;
    XT[xt2_idx(f, r)] = f2bf(acc);
    float p = acc * av[f];
    #pragma unroll
    for (int o = 32; o > 0; o >>= 1) p += __shfl_xor(p, o, 64);
    if (f == 0) dout[r] = p;
  }
}

// ---------------- K2: global maxes of Whst (->mx[0]) and Whtt (->mx[1])
__global__ __launch_bounds__(256) void max_kernel(
    const float* __restrict__ Whst, const float* __restrict__ Whtt, float* __restrict__ mx)
{
  const float* src = blockIdx.x == 0 ? Whst : Whtt;
  int n = blockIdx.x == 0 ? N_S : N_T;
  int t = threadIdx.x;
  float m = -1e30f;
  for (int i = t; i < n; i += 256) m = fmaxf(m, src[i]);
  __shared__ float red[4];
  #pragma unroll
  for (int o = 32; o > 0; o >>= 1) m = fmaxf(m, __shfl_xor(m, o, 64));
  if ((t & 63) == 0) red[t >> 6] = m;
  __syncthreads();
  if (t == 0) mx[blockIdx.x] = fmaxf(fmaxf(red[0], red[1]), fmaxf(red[2], red[3]));
}

// ---------------- K3: fused both-direction masked-softmax aggregation via MFMA bf16.
// w = bit * exp(lrelu(baseU[u]+valK[k]) - lrelu(baseU[u]+mother)), arg <= 0 always.
// Denominators via ones-B MFMA. No atomics: partials per k-split block.
template<int DIR>
__device__ __forceinline__ void agg_body(
    int rb, int split,
    const u64* __restrict__ MBt,
    const float* __restrict__ baseU,
    const float* __restrict__ valK,
    const unsigned short* __restrict__ XT2,
    float mother,
    float* __restrict__ accP,   // [SPL][NU][NF]
    float* __restrict__ sumP)   // [SPL][NU]
{
  constexpr int NK = (DIR == 0) ? N_S : N_T;
  constexpr int NU = (DIR == 0) ? N_T : N_S;
  constexpr int SPL = (DIR == 0) ? SPL0 : SPL1;
  constexpr int KCH = NK / SPL;
  int t = threadIdx.x;
  int wave = t >> 6, l = t & 63;
  int row16 = l & 15, grp = l >> 4;
  int u = rb*64 + wave*16 + row16;
  float bu = baseU[u];
  float Mu = lrelu(bu + mother);
  f32x4 acc[4];
  #pragma unroll
  for (int q = 0; q < 4; ++q) { acc[q][0]=0.f; acc[q][1]=0.f; acc[q][2]=0.f; acc[q][3]=0.f; }
  f32x4 accs; accs[0]=0.f; accs[1]=0.f; accs[2]=0.f; accs[3]=0.f;
  short8 bones;
  #pragma unroll
  for (int j = 0; j < 8; ++j) bones[j] = (short)0x3F80;   // bf16(1.0)
  int kc0 = split * KCH;

  #pragma unroll 2
  for (int k0 = kc0; k0 < kc0 + KCH; k0 += 64) {
    u64 mb = MBt[(size_t)(k0 >> 6)*NU + u];        // 128B contiguous per quarter-wave
    short8 af0, af1;
    #pragma unroll
    for (int h = 0; h < 2; ++h) {
      int kb = k0 + 32*h + grp*8;
      float4 v0 = *(const float4*)&valK[kb];
      float4 v1 = *(const float4*)&valK[kb + 4];
      float vv[8] = {v0.x, v0.y, v0.z, v0.w, v1.x, v1.y, v1.z, v1.w};
      unsigned bbits = (unsigned)(mb >> (grp*8 + 32*h)) & 0xffu;
      short8 af;
      #pragma unroll
      for (int j = 0; j < 8; ++j) {
        float x = bu + vv[j];
        float e = __expf(lrelu(x) - Mu);
        float wv = ((bbits >> j) & 1u) ? e : 0.f;
        af[j] = (short)f2bf(wv);
      }
      if (h == 0) af0 = af; else af1 = af;
    }
    const unsigned short* xb = XT2 + ((size_t)(k0 >> 5))*2048 + l*8;
    #pragma unroll
    for (int q = 0; q < 4; ++q) {
      short8 b0 = *(const short8*)(xb + q*512);          // 1KB contiguous per wave
      short8 b1 = *(const short8*)(xb + 2048 + q*512);
      acc[q] = __builtin_amdgcn_mfma_f32_16x16x32_bf16(af0, b0, acc[q], 0, 0, 0);
      acc[q] = __builtin_amdgcn_mfma_f32_16x16x32_bf16(af1, b1, acc[q], 0, 0, 0);
    }
    accs = __builtin_amdgcn_mfma_f32_16x16x32_bf16(af0, bones, accs, 0, 0, 0);
    accs = __builtin_amdgcn_mfma_f32_16x16x32_bf16(af1, bones, accs, 0, 0, 0);
  }

  if (row16 == 0) {
    #pragma unroll
    for (int r = 0; r < 4; ++r)
      sumP[(size_t)split*NU + rb*64 + wave*16 + grp*4 + r] = accs[r];
  }
  float* ap = accP + (size_t)split*NU*NF;
  #pragma unroll
  for (int q = 0; q < 4; ++q) {
    #pragma unroll
    for (int r = 0; r < 4; ++r) {
      int uo = rb*64 + wave*16 + grp*4 + r;
      ap[(size_t)uo*NF + q*16 + row16] = acc[q][r];
    }
  }
}

__global__ __launch_bounds__(256, 8) void agg_fused(
    const u64* __restrict__ RBt, const u64* __restrict__ CBt,
    const float* __restrict__ Whst, const float* __restrict__ Whtt,
    const unsigned short* __restrict__ XT2s, const unsigned short* __restrict__ XT2t,
    const float* __restrict__ mx,
    float* __restrict__ P0, float* __restrict__ S0,
    float* __restrict__ P1, float* __restrict__ S1)
{
  int b = blockIdx.x;
  if (b < 64*SPL0) {
    agg_body<0>(b & 63, b >> 6, RBt, Whtt, Whst, XT2s, mx[0], P0, S0);
  } else {
    int b2 = b - 64*SPL0;
    agg_body<1>(b2 & 127, b2 >> 7, CBt, Whst, Whtt, XT2t, mx[1], P1, S1);
  }
}

// ---------------- K4: reduce partials + normalize + bias + elu, float4-vectorized
__global__ __launch_bounds__(256) void finalize_kernel(
    const float* __restrict__ P0, const float* __restrict__ S0,
    const float* __restrict__ P1, const float* __restrict__ S1,
    const float* __restrict__ bias_s, const float* __restrict__ bias_t,
    float* __restrict__ out)
{
  int tid = blockIdx.x*256 + threadIdx.x;   // one float4 per thread
  const int n0 = N_T*NF/4;
  float4 a = make_float4(0.f, 0.f, 0.f, 0.f);
  float den = 0.f;
  float4 bias;
  if (tid < n0) {
    int u = tid >> 4, fq = (tid & 15)*4;
    #pragma unroll
    for (int s = 0; s < SPL0; ++s) {
      float4 p = *(const float4*)&P0[((size_t)s*N_T + u)*NF + fq];
      a.x += p.x; a.y += p.y; a.z += p.z; a.w += p.w;
      den += S0[(size_t)s*N_T + u];
    }
    bias = *(const float4*)&bias_s[fq];
  } else {
    int i2 = tid - n0;
    int u = i2 >> 4, fq = (i2 & 15)*4;
    #pragma unroll
    for (int s = 0; s < SPL1; ++s) {
      float4 p = *(const float4*)&P1[((size_t)s*N_S + u)*NF + fq];
      a.x += p.x; a.y += p.y; a.z += p.z; a.w += p.w;
      den += S1[(size_t)s*N_S + u];
    }
    bias = *(const float4*)&bias_t[fq];
  }
  float inv = den > 0.f ? 1.f/den : 0.f;
  float4 v;
  v.x = a.x*inv + bias.x; v.y = a.y*inv + bias.y;
  v.z = a.z*inv + bias.z; v.w = a.w*inv + bias.w;
  v.x = v.x > 0.f ? v.x : expm1f(v.x);
  v.y = v.y > 0.f ? v.y : expm1f(v.y);
  v.z = v.z > 0.f ? v.z : expm1f(v.z);
  v.w = v.w > 0.f ? v.w : expm1f(v.w);
  *(float4*)&out[tid*4] = v;
}

extern "C" void kernel_launch(void* const* d_in, const int* in_sizes, int n_in,
                              void* d_out, int out_size, void* d_ws, size_t ws_size,
                              hipStream_t stream)
{
  const float* hs     = (const float*)d_in[0];
  const float* ht     = (const float*)d_in[1];
  const int*   A      = (const int*)  d_in[2];
  const float* Ws     = (const float*)d_in[3];
  const float* Wt     = (const float*)d_in[4];
  const float* a1     = (const float*)d_in[5];
  const float* bias_s = (const float*)d_in[6];
  const float* bias_t = (const float*)d_in[7];
  float* out = (float*)d_out;

  u64* RBt = (u64*)d_ws;                                     // (N_S/64)*N_T = 4MB
  u64* CBt = RBt + (size_t)(N_S/64)*N_T;                     // (N_T/64)*N_S = 4MB
  unsigned short* XT2s = (unsigned short*)(CBt + (size_t)(N_T/64)*N_S); // 1MB
  unsigned short* XT2t = XT2s + (size_t)NF*N_S;              // 0.5MB
  float* Whst  = (float*)(XT2t + (size_t)NF*N_T);            // 8192
  float* Whtt  = Whst + N_S;                                 // 4096
  float* mx    = Whtt + N_T;                                 // 16 (padded)
  float* P0    = mx + 16;                                    // SPL0*4096*64 = 8MB
  float* S0    = P0 + (size_t)SPL0*N_T*NF;                   // SPL0*4096
  float* P1    = S0 + (size_t)SPL0*N_T;                      // SPL1*8192*64 = 16MB
  float* S1    = P1 + (size_t)SPL1*N_S*NF;                   // SPL1*8192

  k1_fused<<<2048 + (N_S + N_T)/4, 256, 0, stream>>>(A, RBt, CBt, hs, ht, Ws, Wt, a1,
                                                     XT2s, XT2t, Whst, Whtt);
  max_kernel<<<2, 256, 0, stream>>>(Whst, Whtt, mx);
  agg_fused<<<64*SPL0 + 128*SPL1, 256, 0, stream>>>(RBt, CBt, Whst, Whtt, XT2s, XT2t, mx,
                                                    P0, S0, P1, S1);
  finalize_kernel<<<(N_T*NF + N_S*NF)/1024, 256, 0, stream>>>(P0, S0, P1, S1,
                                                              bias_s, bias_t, out);
}

// Round 6
// 89.575 us; speedup vs baseline: 2.2120x; 1.1278x over previous
//
#include <hip/hip_runtime.h>
#include <math.h>

#define N_S 8192
#define N_T 4096
#define DIN 128
#define NF  64
#define SPL0 8
#define SPL1 8

typedef __attribute__((ext_vector_type(8))) short short8;
typedef __attribute__((ext_vector_type(4))) float f32x4;
typedef unsigned long long u64;
typedef unsigned int u32;

// round-to-nearest-even f32 -> bf16 bits (used for XT2 features only)
__device__ __forceinline__ unsigned short f2bf(float x){
  unsigned u = __float_as_uint(x);
  unsigned r = (u + 0x7fffu + ((u >> 16) & 1u)) >> 16;
  return (unsigned short)r;
}

// fragment-major bf16 layout: B-frag for MFMA reads 1KB contiguous per wave
// idx(f,k) = (k>>5)*2048 + (f>>4)*512 + ((k>>3)&3)*128 + (f&15)*8 + (k&7)
__device__ __forceinline__ size_t xt2_idx(int f, int k){
  return ((size_t)(k >> 5))*2048 + (size_t)((f >> 4)*512 + ((k >> 3) & 3)*128 + (f & 15)*8 + (k & 7));
}

// ---------------- K1: fused {compact A -> bitmasks} + {projections}
// blocks [0,2048): compact 64x256 tile of A into RBt (k-chunk-major) and CBt
// blocks [2048,5120): proj 4 rows -> XT2 (fragment-major bf16) + exp tables
//   E[r]=exp(Wh@a), F[r]=exp(0.1*(Wh@a))  (no softmax max-shift needed: args bounded ~20)
__global__ __launch_bounds__(256) void k1_fused(
    const int* __restrict__ A,
    u64* __restrict__ RBt,       // [N_S/64][N_T]  bits of row i over j, chunk-major
    u64* __restrict__ CBt,       // [N_T/64][N_S]  bits of col j over i, chunk-major
    const float* __restrict__ hs, const float* __restrict__ ht,
    const float* __restrict__ Ws, const float* __restrict__ Wt,
    const float* __restrict__ a1,
    unsigned short* __restrict__ XT2s, unsigned short* __restrict__ XT2t,
    float* __restrict__ Es, float* __restrict__ Fs,
    float* __restrict__ Et, float* __restrict__ Ft)
{
  __shared__ __align__(16) float smem[DIN*NF + 4*DIN];   // 34816 B
  int bx = blockIdx.x;
  int t = threadIdx.x;
  if (bx < 2048) {
    // ---- compact ----
    unsigned* T4 = (unsigned*)smem;      // 16*65 words
    int i0 = (bx & 63) * 64;
    int j0 = (bx >> 6) * 256;
    int w = t >> 6, l = t & 63;
    int4 v[16];
    #pragma unroll
    for (int it = 0; it < 16; ++it)
      v[it] = *(const int4*)&A[(size_t)(i0 + w*16 + it)*N_S + j0 + 4*l];
    #pragma unroll
    for (int rg = 0; rg < 4; ++rg) {
      unsigned p = 0;
      #pragma unroll
      for (int rr = 0; rr < 4; ++rr) {
        int4 m = v[rg*4 + rr];
        unsigned nib = (m.x > 0 ? 1u : 0u) | (m.y > 0 ? 2u : 0u)
                     | (m.z > 0 ? 4u : 0u) | (m.w > 0 ? 8u : 0u);
        p |= nib << (8*rr);
      }
      T4[(w*4 + rg)*65 + l] = p;
    }
    __syncthreads();
    // RB: thread -> row r = t&63, colgroup g = t>>6
    {
      int r = t & 63, g = t >> 6;
      u64 bits = 0;
      #pragma unroll
      for (int i = 0; i < 16; ++i) {
        unsigned word = T4[(r >> 2)*65 + g*16 + i];
        unsigned nib = (word >> (8*(r & 3))) & 0xFu;
        bits |= (u64)nib << (4*i);
      }
      RBt[(size_t)((j0 >> 6) + g)*N_T + i0 + r] = bits;
    }
    // CB: thread -> col c = t
    {
      int c = t;
      u64 bits = 0;
      #pragma unroll
      for (int rg = 0; rg < 16; ++rg) {
        unsigned word = T4[rg*65 + (c >> 2)];
        unsigned x = (word >> (c & 3)) & 0x01010101u;
        unsigned nib = (x * 0x01020408u) >> 24;
        bits |= (u64)(nib & 0xFu) << (4*rg);
      }
      CBt[(size_t)(i0 >> 6)*N_S + j0 + c] = bits;
    }
  } else {
    // ---- proj ----
    int b = bx - 2048;
    float* Wl = smem;
    float* hrow = smem + DIN*NF;
    bool is_s = b < (N_S/4);
    const float* h; const float* W; const float* av;
    unsigned short* XT; float* Ed; float* Fd; int r0;
    if (is_s) { r0 = b*4;           h = hs; W = Ws; av = a1 + 64; XT = XT2s; Ed = Es; Fd = Fs; }
    else      { r0 = (b - N_S/4)*4; h = ht; W = Wt; av = a1;      XT = XT2t; Ed = Et; Fd = Ft; }
    for (int i = t; i < DIN*NF; i += 256) Wl[i] = W[i];
    for (int i = t; i < 4*DIN;  i += 256) hrow[i] = h[(size_t)r0*DIN + i];
    __syncthreads();
    int f = t & 63, sr = t >> 6;
    float acc = 0.f;
    #pragma unroll 8
    for (int k = 0; k < DIN; ++k) acc += hrow[sr*DIN + k] * Wl[k*NF + f];
    int r = r0 + sr;
    XT[xt2_idx(f, r)] = f2bf(acc);
    float p = acc * av[f];
    #pragma unroll
    for (int o = 32; o > 0; o >>= 1) p += __shfl_xor(p, o, 64);
    if (f == 0) { Ed[r] = __expf(p); Fd[r] = __expf(0.1f*p); }
  }
}

// ---------------- K2: fused both-direction masked aggregation via MFMA bf16.
// w(u,k) = bit(u,k) * exp(lrelu(bu+vk)) = bit * max(Eu*Ek, Fu*Fk)   [exp monotone]
// Softmax ratio is shift-invariant, so no max subtraction needed (args bounded).
// Denominators via ones-B MFMA. No atomics: partials per k-split block.
template<int DIR>
__device__ __forceinline__ void agg_body(
    int rb, int split,
    const u64* __restrict__ MBt,
    const float* __restrict__ EuT, const float* __restrict__ FuT,
    const float* __restrict__ EkT, const float* __restrict__ FkT,
    const unsigned short* __restrict__ XT2,
    float* __restrict__ accP,   // [SPL][NU][NF]
    float* __restrict__ sumP)   // [SPL][NU]
{
  constexpr int NK = (DIR == 0) ? N_S : N_T;
  constexpr int NU = (DIR == 0) ? N_T : N_S;
  constexpr int SPL = (DIR == 0) ? SPL0 : SPL1;
  constexpr int KCH = NK / SPL;
  int t = threadIdx.x;
  int wave = t >> 6, l = t & 63;
  int row16 = l & 15, grp = l >> 4;
  int u = rb*64 + wave*16 + row16;
  float Eu = EuT[u], Fu = FuT[u];
  f32x4 acc[4];
  #pragma unroll
  for (int q = 0; q < 4; ++q) { acc[q][0]=0.f; acc[q][1]=0.f; acc[q][2]=0.f; acc[q][3]=0.f; }
  f32x4 accs; accs[0]=0.f; accs[1]=0.f; accs[2]=0.f; accs[3]=0.f;
  short8 bones;
  #pragma unroll
  for (int j = 0; j < 8; ++j) bones[j] = (short)0x3F80;   // bf16(1.0)
  int kc0 = split * KCH;

  #pragma unroll 2
  for (int k0 = kc0; k0 < kc0 + KCH; k0 += 64) {
    u64 mb = MBt[(size_t)(k0 >> 6)*NU + u];        // 128B contiguous per quarter-wave
    u32 mlo = (u32)mb, mhi = (u32)(mb >> 32);
    short8 af01[2];
    #pragma unroll
    for (int h = 0; h < 2; ++h) {
      int kb = k0 + 32*h + grp*8;
      float4 e0 = *(const float4*)&EkT[kb];
      float4 e1 = *(const float4*)&EkT[kb + 4];
      float4 f0 = *(const float4*)&FkT[kb];
      float4 f1 = *(const float4*)&FkT[kb + 4];
      float w0 = fmaxf(Eu*e0.x, Fu*f0.x);
      float w1 = fmaxf(Eu*e0.y, Fu*f0.y);
      float w2 = fmaxf(Eu*e0.z, Fu*f0.z);
      float w3 = fmaxf(Eu*e0.w, Fu*f0.w);
      float w4 = fmaxf(Eu*e1.x, Fu*f1.x);
      float w5 = fmaxf(Eu*e1.y, Fu*f1.y);
      float w6 = fmaxf(Eu*e1.z, Fu*f1.z);
      float w7 = fmaxf(Eu*e1.w, Fu*f1.w);
      u32 bb = ((h ? mhi : mlo) >> (grp*8)) & 0xffu;
      float wv[8] = {w0,w1,w2,w3,w4,w5,w6,w7};
      union { u32 uu[4]; short8 v; } pk;
      #pragma unroll
      for (int p = 0; p < 4; ++p) {
        int j = 2*p;
        int slo = ((int)(bb << (31 - j))) >> 31;        // 0 or -1 from bit j
        int shi = ((int)(bb << (30 - j))) >> 31;        // 0 or -1 from bit j+1
        u32 msk = __builtin_amdgcn_perm((u32)shi, (u32)slo, 0x05040100u); // [shi16|slo16]
        u32 w01 = __builtin_amdgcn_perm(__float_as_uint(wv[j+1]),
                                        __float_as_uint(wv[j]), 0x07060302u); // trunc bf16 pair
        pk.uu[p] = w01 & msk;
      }
      af01[h] = pk.v;
    }
    const unsigned short* xb = XT2 + ((size_t)(k0 >> 5))*2048 + l*8;
    #pragma unroll
    for (int q = 0; q < 4; ++q) {
      short8 b0 = *(const short8*)(xb + q*512);          // 1KB contiguous per wave
      short8 b1 = *(const short8*)(xb + 2048 + q*512);
      acc[q] = __builtin_amdgcn_mfma_f32_16x16x32_bf16(af01[0], b0, acc[q], 0, 0, 0);
      acc[q] = __builtin_amdgcn_mfma_f32_16x16x32_bf16(af01[1], b1, acc[q], 0, 0, 0);
    }
    accs = __builtin_amdgcn_mfma_f32_16x16x32_bf16(af01[0], bones, accs, 0, 0, 0);
    accs = __builtin_amdgcn_mfma_f32_16x16x32_bf16(af01[1], bones, accs, 0, 0, 0);
  }

  if (row16 == 0) {
    #pragma unroll
    for (int r = 0; r < 4; ++r)
      sumP[(size_t)split*NU + rb*64 + wave*16 + grp*4 + r] = accs[r];
  }
  float* ap = accP + (size_t)split*NU*NF;
  #pragma unroll
  for (int q = 0; q < 4; ++q) {
    #pragma unroll
    for (int r = 0; r < 4; ++r) {
      int uo = rb*64 + wave*16 + grp*4 + r;
      ap[(size_t)uo*NF + q*16 + row16] = acc[q][r];
    }
  }
}

__global__ __launch_bounds__(256, 8) void agg_fused(
    const u64* __restrict__ RBt, const u64* __restrict__ CBt,
    const float* __restrict__ Es, const float* __restrict__ Fs,
    const float* __restrict__ Et, const float* __restrict__ Ft,
    const unsigned short* __restrict__ XT2s, const unsigned short* __restrict__ XT2t,
    float* __restrict__ P0, float* __restrict__ S0,
    float* __restrict__ P1, float* __restrict__ S1)
{
  int b = blockIdx.x;
  if (b < 64*SPL0) {
    agg_body<0>(b & 63, b >> 6, RBt, Et, Ft, Es, Fs, XT2s, P0, S0);
  } else {
    int b2 = b - 64*SPL0;
    agg_body<1>(b2 & 127, b2 >> 7, CBt, Es, Fs, Et, Ft, XT2t, P1, S1);
  }
}

// ---------------- K3: reduce partials + normalize + bias + elu, float4-vectorized
__global__ __launch_bounds__(256) void finalize_kernel(
    const float* __restrict__ P0, const float* __restrict__ S0,
    const float* __restrict__ P1, const float* __restrict__ S1,
    const float* __restrict__ bias_s, const float* __restrict__ bias_t,
    float* __restrict__ out)
{
  int tid = blockIdx.x*256 + threadIdx.x;   // one float4 per thread
  const int n0 = N_T*NF/4;
  float4 a = make_float4(0.f, 0.f, 0.f, 0.f);
  float den = 0.f;
  float4 bias;
  if (tid < n0) {
    int u = tid >> 4, fq = (tid & 15)*4;
    #pragma unroll
    for (int s = 0; s < SPL0; ++s) {
      float4 p = *(const float4*)&P0[((size_t)s*N_T + u)*NF + fq];
      a.x += p.x; a.y += p.y; a.z += p.z; a.w += p.w;
      den += S0[(size_t)s*N_T + u];
    }
    bias = *(const float4*)&bias_s[fq];
  } else {
    int i2 = tid - n0;
    int u = i2 >> 4, fq = (i2 & 15)*4;
    #pragma unroll
    for (int s = 0; s < SPL1; ++s) {
      float4 p = *(const float4*)&P1[((size_t)s*N_S + u)*NF + fq];
      a.x += p.x; a.y += p.y; a.z += p.z; a.w += p.w;
      den += S1[(size_t)s*N_S + u];
    }
    bias = *(const float4*)&bias_t[fq];
  }
  float inv = den > 0.f ? 1.f/den : 0.f;
  float4 v;
  v.x = a.x*inv + bias.x; v.y = a.y*inv + bias.y;
  v.z = a.z*inv + bias.z; v.w = a.w*inv + bias.w;
  v.x = v.x > 0.f ? v.x : expm1f(v.x);
  v.y = v.y > 0.f ? v.y : expm1f(v.y);
  v.z = v.z > 0.f ? v.z : expm1f(v.z);
  v.w = v.w > 0.f ? v.w : expm1f(v.w);
  *(float4*)&out[tid*4] = v;
}

extern "C" void kernel_launch(void* const* d_in, const int* in_sizes, int n_in,
                              void* d_out, int out_size, void* d_ws, size_t ws_size,
                              hipStream_t stream)
{
  const float* hs     = (const float*)d_in[0];
  const float* ht     = (const float*)d_in[1];
  const int*   A      = (const int*)  d_in[2];
  const float* Ws     = (const float*)d_in[3];
  const float* Wt     = (const float*)d_in[4];
  const float* a1     = (const float*)d_in[5];
  const float* bias_s = (const float*)d_in[6];
  const float* bias_t = (const float*)d_in[7];
  float* out = (float*)d_out;

  u64* RBt = (u64*)d_ws;                                     // (N_S/64)*N_T = 4MB
  u64* CBt = RBt + (size_t)(N_S/64)*N_T;                     // (N_T/64)*N_S = 4MB
  unsigned short* XT2s = (unsigned short*)(CBt + (size_t)(N_T/64)*N_S); // 1MB
  unsigned short* XT2t = XT2s + (size_t)NF*N_S;              // 0.5MB
  float* Es = (float*)(XT2t + (size_t)NF*N_T);               // 8192
  float* Fs = Es + N_S;                                      // 8192
  float* Et = Fs + N_S;                                      // 4096
  float* Ft = Et + N_T;                                      // 4096
  float* P0 = Ft + N_T;                                      // SPL0*4096*64 = 8MB
  float* S0 = P0 + (size_t)SPL0*N_T*NF;                      // SPL0*4096
  float* P1 = S0 + (size_t)SPL0*N_T;                         // SPL1*8192*64 = 16MB
  float* S1 = P1 + (size_t)SPL1*N_S*NF;                      // SPL1*8192

  k1_fused<<<2048 + (N_S + N_T)/4, 256, 0, stream>>>(A, RBt, CBt, hs, ht, Ws, Wt, a1,
                                                     XT2s, XT2t, Es, Fs, Et, Ft);
  agg_fused<<<64*SPL0 + 128*SPL1, 256, 0, stream>>>(RBt, CBt, Es, Fs, Et, Ft,
                                                    XT2s, XT2t, P0, S0, P1, S1);
  finalize_kernel<<<(N_T*NF + N_S*NF)/1024, 256, 0, stream>>>(P0, S0, P1, S1,
                                                              bias_s, bias_t, out);
}